// Round 1
// baseline (1314.927 us; speedup 1.0000x reference)
//
#include <hip/hip_runtime.h>
#include <stdint.h>
#include <math.h>

#define NN 6144
#define JJ 2000
#define HH 100
// Big-K layout: cols [0,100)=Q(or K) block, [100,128)=zero, [128,2128)=xn, [2128,2176)=zero
#define KB 2176
#define XOFF 128
#define KQK 2048   // K for QK-projection GEMM: xn cols (2000) + zero pad, read at A+XOFF

typedef __bf16 bf16;
typedef __bf16 bf16x8 __attribute__((ext_vector_type(8)));
typedef float f32x4 __attribute__((ext_vector_type(4)));

__device__ __forceinline__ void load_lds16(const void* g, void* l) {
  __builtin_amdgcn_global_load_lds(
      (const __attribute__((address_space(1))) void*)(uintptr_t)g,
      (__attribute__((address_space(3))) void*)(uint32_t)(uintptr_t)l,
      16, 0, 0);
}

// ---------------------------------------------------------------------------
// Legacy 128x128 kernel (kept for MODE 3: QK projection, N=256 only).
// ---------------------------------------------------------------------------
template <int MODE>
__global__ __launch_bounds__(256, 2) void gemm_bt(
    const bf16* __restrict__ A, const bf16* __restrict__ B,
    int lda, int ldb, int kdim,
    const float* __restrict__ p0, const float* __restrict__ p1,
    const float* __restrict__ p2,
    bf16* __restrict__ ob0, bf16* __restrict__ ob1,
    float* __restrict__ of0, float* __restrict__ rowsum)
{
  __shared__ alignas(16) bf16 As[128 * 64];
  __shared__ alignas(16) bf16 Bs[128 * 64];

  const int tid = threadIdx.x;
  const int lane = tid & 63;
  const int wv = tid >> 6;
  const int m0 = blockIdx.x * 128;
  const int n0 = blockIdx.y * 128;

  const int srow = lane >> 3;
  const int scol = ((lane & 7) ^ srow) * 8;
  const bf16* gA = A + (size_t)(m0 + wv * 32 + srow) * lda + scol;
  const bf16* gB = B + (size_t)(n0 + wv * 32 + srow) * ldb + scol;
  bf16* lA0 = &As[(wv * 32) * 64];
  bf16* lB0 = &Bs[(wv * 32) * 64];

  const int l15 = lane & 15;
  const int l4 = lane >> 4;
  const int s7 = l15 & 7;
  const int wm = (wv >> 1) * 64;
  const int wn = (wv & 1) * 64;
  const bf16* ra0 = &As[(wm + l15) * 64 + ((l4 ^ s7) * 8)];
  const bf16* ra1 = &As[(wm + l15) * 64 + (((l4 + 4) ^ s7) * 8)];
  const bf16* rb0 = &Bs[(wn + l15) * 64 + ((l4 ^ s7) * 8)];
  const bf16* rb1 = &Bs[(wn + l15) * 64 + (((l4 + 4) ^ s7) * 8)];

  f32x4 acc[4][4];
#pragma unroll
  for (int i = 0; i < 4; ++i)
#pragma unroll
    for (int j = 0; j < 4; ++j) acc[i][j] = {0.f, 0.f, 0.f, 0.f};

  const int kiters = kdim >> 6;
  for (int kt = 0; kt < kiters; ++kt) {
    __syncthreads();
#pragma unroll
    for (int it = 0; it < 4; ++it) {
      load_lds16(gA + (size_t)it * 8 * lda, lA0 + it * 512);
      load_lds16(gB + (size_t)it * 8 * ldb, lB0 + it * 512);
    }
    gA += 64;
    gB += 64;
    __syncthreads();
#pragma unroll
    for (int ks = 0; ks < 2; ++ks) {
      const bf16* ra = ks ? ra1 : ra0;
      const bf16* rb = ks ? rb1 : rb0;
      bf16x8 af[4], bb[4];
#pragma unroll
      for (int i = 0; i < 4; ++i)
        af[i] = *(const bf16x8*)(ra + i * 1024);
#pragma unroll
      for (int j = 0; j < 4; ++j)
        bb[j] = *(const bf16x8*)(rb + j * 1024);
#pragma unroll
      for (int i = 0; i < 4; ++i)
#pragma unroll
        for (int j = 0; j < 4; ++j)
          acc[i][j] = __builtin_amdgcn_mfma_f32_16x16x32_bf16(af[i], bb[j], acc[i][j], 0, 0, 0);
    }
  }

  const int row_base = m0 + wm + l4 * 4;
  const int col_base = n0 + wn + l15;

  if (MODE == 0) {
    // unused in this build
  } else if (MODE == 1) {
    // unused in this build
  } else if (MODE == 2) {
    // unused in this build
  } else {
#pragma unroll
    for (int i = 0; i < 4; ++i) {
#pragma unroll
      for (int r = 0; r < 4; ++r) {
        int row = row_base + i * 16 + r;
        float nm = p0[row];
#pragma unroll
        for (int j = 0; j < 4; ++j) {
          int h = col_base + j * 16;
          float v = acc[i][j][r] * nm;
          if (h < HH) ob0[(size_t)row * KB + h] = (bf16)((v + p1[h]) * 0.1f);
          else if (h < 2 * HH) ob1[(size_t)row * KB + (h - HH)] = (bf16)(v + p2[h - HH]);
        }
      }
    }
  }
}

// ---------------------------------------------------------------------------
// 256x256 8-phase pipelined GEMM core (T2 swizzle + T3/T4 counted-vmcnt + T5).
// C[i,j] = sum_k A[i,k]*B[j,k]; 8 waves (2M x 4N), wave tile 128x64, BK=64.
// LDS: 2 buffers x (A 256x64 + B 256x64) bf16 = 128 KiB, 16B-chunk XOR swizzle
// (phys_chunk = log_chunk ^ (row&7)); staging pre-swizzles the GLOBAL column.
// Per tile: 4 quadrant phases x 16 MFMA. Stage slots (tile T):
//   ph1: (T+1).B1   ph2: --   ph3: (T+2).B0   ph4: (T+2).A0,(T+2).A1
// Each stage writes a region whose last ds_read retired (lgkmcnt0+barrier) in
// an earlier phase -> deterministically race-free. vmcnt(6) only at tile
// boundaries (3 half-tiles = 6 loads stay in flight across barriers).
// ---------------------------------------------------------------------------
__device__ __forceinline__ void gemm256_core(
    const bf16* __restrict__ A, const bf16* __restrict__ B,
    int lda, int ldb, int kdim, int m0, int n0, f32x4 (&acc)[8][4])
{
  __shared__ alignas(16) bf16 As[2][256 * 64];
  __shared__ alignas(16) bf16 Bs[2][256 * 64];

  const int tid = threadIdx.x;
  const int lane = tid & 63;
  const int wv = tid >> 6;        // 0..7
  const int wm = wv >> 2;         // 0..1 (M)
  const int wn = wv & 3;          // 0..3 (N)
  const int l15 = lane & 15;
  const int l4 = lane >> 4;
  const int s7 = lane & 7;
  const int srow = lane >> 3;
  const int scol = ((lane & 7) ^ srow) * 8;

  const bf16* gA = A + (size_t)(m0 + wv * 8 + srow) * lda + scol;
  const bf16* gB = B + (size_t)(n0 + wv * 8 + srow) * ldb + scol;

  const int c0 = (l4 ^ s7) * 8;         // ks=0 swizzled chunk byte offset /2
  const int c1 = ((l4 + 4) ^ s7) * 8;   // ks=1

#pragma unroll
  for (int i = 0; i < 8; ++i)
#pragma unroll
    for (int j = 0; j < 4; ++j) acc[i][j] = {0.f, 0.f, 0.f, 0.f};

  const int kt = kdim >> 6;

  // one macro call = 2 global_load_lds = one 128-row half-tile
#define SA_(bufi, h, T)                                                        \
  do {                                                                         \
    load_lds16(gA + (size_t)((h) * 128) * lda + (size_t)(T) * 64,              \
               &As[(bufi)][(wv * 8 + (h) * 128) * 64]);                        \
    load_lds16(gA + (size_t)((h) * 128 + 64) * lda + (size_t)(T) * 64,         \
               &As[(bufi)][(wv * 8 + (h) * 128 + 64) * 64]);                   \
  } while (0)
#define SB_(bufi, h, T)                                                        \
  do {                                                                         \
    load_lds16(gB + (size_t)((h) * 128) * ldb + (size_t)(T) * 64,              \
               &Bs[(bufi)][(wv * 8 + (h) * 128) * 64]);                        \
    load_lds16(gB + (size_t)((h) * 128 + 64) * ldb + (size_t)(T) * 64,         \
               &Bs[(bufi)][(wv * 8 + (h) * 128 + 64) * 64]);                   \
  } while (0)

  // prologue: tile0 {B0,A0,B1,A1} (8 loads) + tile1 {B0,A0,A1} (6 loads)
  SB_(0, 0, 0); SA_(0, 0, 0); SB_(0, 1, 0); SA_(0, 1, 0);
  SB_(1, 0, 1); SA_(1, 0, 1); SA_(1, 1, 1);
  asm volatile("s_waitcnt vmcnt(6)" ::: "memory");   // tile0 resident
  __builtin_amdgcn_s_barrier();

  bf16x8 af[4][2], b0[2][2], b1[2][2];

  for (int t2 = 0; t2 < kt; t2 += 2) {
#pragma unroll
    for (int u = 0; u < 2; ++u) {
      const int T = t2 + u;
      const int buf = u, bufn = u ^ 1;
      const bf16* pA = &As[buf][(wm * 128 + l15) * 64];
      const bf16* pB = &Bs[buf][(wn * 64 + l15) * 64];

      // -------- phase 1: quadrant (mh0,nh0); stage (T+1).B1 --------
#pragma unroll
      for (int fm = 0; fm < 4; ++fm) {
        af[fm][0] = *(const bf16x8*)(pA + (fm * 16) * 64 + c0);
        af[fm][1] = *(const bf16x8*)(pA + (fm * 16) * 64 + c1);
      }
#pragma unroll
      for (int fn = 0; fn < 2; ++fn) {
        b0[fn][0] = *(const bf16x8*)(pB + (fn * 16) * 64 + c0);
        b0[fn][1] = *(const bf16x8*)(pB + (fn * 16) * 64 + c1);
      }
      if (T + 1 < kt) SB_(bufn, 1, T + 1);
      __builtin_amdgcn_s_barrier();
      asm volatile("s_waitcnt lgkmcnt(0)" ::: "memory");
      __builtin_amdgcn_sched_barrier(0);
      __builtin_amdgcn_s_setprio(1);
#pragma unroll
      for (int ks = 0; ks < 2; ++ks)
#pragma unroll
        for (int fm = 0; fm < 4; ++fm)
#pragma unroll
          for (int fn = 0; fn < 2; ++fn)
            acc[fm][fn] = __builtin_amdgcn_mfma_f32_16x16x32_bf16(
                af[fm][ks], b0[fn][ks], acc[fm][fn], 0, 0, 0);
      __builtin_amdgcn_s_setprio(0);
      __builtin_amdgcn_s_barrier();

      // -------- phase 2: quadrant (mh0,nh1); no stage --------
#pragma unroll
      for (int fn = 0; fn < 2; ++fn) {
        b1[fn][0] = *(const bf16x8*)(pB + ((32 + fn * 16) * 64) + c0);
        b1[fn][1] = *(const bf16x8*)(pB + ((32 + fn * 16) * 64) + c1);
      }
      __builtin_amdgcn_s_barrier();
      asm volatile("s_waitcnt lgkmcnt(0)" ::: "memory");
      __builtin_amdgcn_sched_barrier(0);
      __builtin_amdgcn_s_setprio(1);
#pragma unroll
      for (int ks = 0; ks < 2; ++ks)
#pragma unroll
        for (int fm = 0; fm < 4; ++fm)
#pragma unroll
          for (int fn = 0; fn < 2; ++fn)
            acc[fm][2 + fn] = __builtin_amdgcn_mfma_f32_16x16x32_bf16(
                af[fm][ks], b1[fn][ks], acc[fm][2 + fn], 0, 0, 0);
      __builtin_amdgcn_s_setprio(0);
      __builtin_amdgcn_s_barrier();

      // -------- phase 3: quadrant (mh1,nh1); stage (T+2).B0 --------
#pragma unroll
      for (int fm = 0; fm < 4; ++fm) {
        af[fm][0] = *(const bf16x8*)(pA + ((64 + fm * 16) * 64) + c0);
        af[fm][1] = *(const bf16x8*)(pA + ((64 + fm * 16) * 64) + c1);
      }
      if (T + 2 < kt) SB_(buf, 0, T + 2);
      __builtin_amdgcn_s_barrier();
      asm volatile("s_waitcnt lgkmcnt(0)" ::: "memory");
      __builtin_amdgcn_sched_barrier(0);
      __builtin_amdgcn_s_setprio(1);
#pragma unroll
      for (int ks = 0; ks < 2; ++ks)
#pragma unroll
        for (int fm = 0; fm < 4; ++fm)
#pragma unroll
          for (int fn = 0; fn < 2; ++fn)
            acc[4 + fm][2 + fn] = __builtin_amdgcn_mfma_f32_16x16x32_bf16(
                af[fm][ks], b1[fn][ks], acc[4 + fm][2 + fn], 0, 0, 0);
      __builtin_amdgcn_s_setprio(0);
      __builtin_amdgcn_s_barrier();

      // -------- phase 4: quadrant (mh1,nh0); stage (T+2).A0,A1; boundary wait
      if (T + 2 < kt) { SA_(buf, 0, T + 2); SA_(buf, 1, T + 2); }
      __builtin_amdgcn_s_barrier();
      __builtin_amdgcn_s_setprio(1);
#pragma unroll
      for (int ks = 0; ks < 2; ++ks)
#pragma unroll
        for (int fm = 0; fm < 4; ++fm)
#pragma unroll
          for (int fn = 0; fn < 2; ++fn)
            acc[4 + fm][fn] = __builtin_amdgcn_mfma_f32_16x16x32_bf16(
                af[fm][ks], b0[fn][ks], acc[4 + fm][fn], 0, 0, 0);
      __builtin_amdgcn_s_setprio(0);
      if (T + 1 < kt) {
        if (T + 2 < kt) asm volatile("s_waitcnt vmcnt(6)" ::: "memory");
        else            asm volatile("s_waitcnt vmcnt(0)" ::: "memory");
      }
      __builtin_amdgcn_s_barrier();
    }
  }
#undef SA_
#undef SB_
}

// Merged logits (z=0) + V-transpose (z=1) launch: independent GEMMs sharing
// B=Bbig; one 1152-block grid packs their tails together (576 @ 1 blk/CU
// alone would waste 25% in round quantization).
__global__ __launch_bounds__(512, 2) void gemm256_lv(
    const bf16* __restrict__ Abig, const bf16* __restrict__ WvT,
    const bf16* __restrict__ Bbig,
    const float* __restrict__ sqv, const float* __restrict__ fv,
    const float* __restrict__ spos, const float* __restrict__ normv,
    const float* __restrict__ bv,
    bf16* __restrict__ P, bf16* __restrict__ Vt, float* __restrict__ rowsum)
{
  const int GB = NN / 256;                 // 24
  int lin = blockIdx.y * GB + blockIdx.x;
  int swz = (lin & 7) * ((GB * GB) / 8) + (lin >> 3);   // XCD swizzle, 576%8==0
  const int m0 = (swz % GB) * 256;
  const int n0 = (swz / GB) * 256;
  const bool isl = (blockIdx.z == 0);

  f32x4 acc[8][4];
  gemm256_core(isl ? Abig : WvT, Bbig, KB, KB, KB, m0, n0, acc);

  const int tid = threadIdx.x;
  const int lane = tid & 63;
  const int wv = tid >> 6;
  const int wm = wv >> 2, wn = wv & 3;
  const int l15 = lane & 15, l4 = lane >> 4;
  const int row_base = m0 + wm * 128 + l4 * 4;
  const int col_base = n0 + wn * 64 + l15;

  if (isl) {
    // logits -> P = exp(QK/dk + cos + spatial + fdiff), rowsum atomics
    float sqc[4], fc[4], pxc[4], pyc[4];
#pragma unroll
    for (int j = 0; j < 4; ++j) {
      int c = col_base + j * 16;
      sqc[j] = sqv[c];
      fc[j] = fv[c];
      pxc[j] = spos[2 * c];
      pyc[j] = spos[2 * c + 1];
    }
#pragma unroll
    for (int i = 0; i < 8; ++i) {
#pragma unroll
      for (int r = 0; r < 4; ++r) {
        int row = row_base + i * 16 + r;
        float sqr = sqv[row], fr = fv[row];
        float pxr = spos[2 * row], pyr = spos[2 * row + 1];
        float rs = 0.f;
#pragma unroll
        for (int j = 0; j < 4; ++j) {
          int c = col_base + j * 16;
          float d2 = fmaxf(sqr + sqc[j] - 2.f * (pxr * pxc[j] + pyr * pyc[j]), 0.f);
          float lg = acc[i][j][r] + __expf(-0.5f * d2) + tanhf(fr - fc[j]);
          float e = __expf(lg);
          P[(size_t)row * NN + c] = (bf16)e;
          rs += e;
        }
        rs += __shfl_xor(rs, 1);
        rs += __shfl_xor(rs, 2);
        rs += __shfl_xor(rs, 4);
        rs += __shfl_xor(rs, 8);
        if (l15 == 0) atomicAdd(&rowsum[row], rs);
      }
    }
  } else {
    // Vt = acc*norm[col] + bv[row]
    float nc[4];
#pragma unroll
    for (int j = 0; j < 4; ++j) nc[j] = normv[col_base + j * 16];
#pragma unroll
    for (int i = 0; i < 8; ++i) {
#pragma unroll
      for (int r = 0; r < 4; ++r) {
        int row = row_base + i * 16 + r;
        float bvr = bv[row];
#pragma unroll
        for (int j = 0; j < 4; ++j)
          Vt[(size_t)row * NN + col_base + j * 16] = (bf16)(acc[i][j][r] * nc[j] + bvr);
      }
    }
  }
}

// out = (P @ V) / rowsum
__global__ __launch_bounds__(512, 2) void gemm256_pv(
    const bf16* __restrict__ Pm, const bf16* __restrict__ Vt,
    const float* __restrict__ rowsum, float* __restrict__ outp)
{
  const int GB = NN / 256;
  int lin = blockIdx.y * GB + blockIdx.x;
  int swz = (lin & 7) * ((GB * GB) / 8) + (lin >> 3);
  const int m0 = (swz % GB) * 256;
  const int n0 = (swz / GB) * 256;

  f32x4 acc[8][4];
  gemm256_core(Pm, Vt, NN, NN, NN, m0, n0, acc);

  const int tid = threadIdx.x;
  const int lane = tid & 63;
  const int wv = tid >> 6;
  const int wm = wv >> 2, wn = wv & 3;
  const int l15 = lane & 15, l4 = lane >> 4;
  const int row_base = m0 + wm * 128 + l4 * 4;
  const int col_base = n0 + wn * 64 + l15;
#pragma unroll
  for (int i = 0; i < 8; ++i) {
#pragma unroll
    for (int r = 0; r < 4; ++r) {
      int row = row_base + i * 16 + r;
      float rinv = 1.f / rowsum[row];
#pragma unroll
      for (int j = 0; j < 4; ++j)
        outp[(size_t)row * NN + col_base + j * 16] = acc[i][j][r] * rinv;
    }
  }
}

// Per-row gene norm + write xn (bf16) into Abig & Bbig at XOFF, zero pads.
__global__ void prep_xn(const float* __restrict__ gene, bf16* __restrict__ Ab,
                        bf16* __restrict__ Bb, float* __restrict__ normv)
{
  int row = blockIdx.x, tid = threadIdx.x;
  const float* g = gene + (size_t)row * JJ;
  float s = 0.f;
  for (int k = tid; k < JJ; k += 256) { float v = g[k]; s += v * v; }
#pragma unroll
  for (int m = 32; m >= 1; m >>= 1) s += __shfl_xor(s, m);
  __shared__ float red[4];
  if ((tid & 63) == 0) red[tid >> 6] = s;
  __syncthreads();
  float tot = red[0] + red[1] + red[2] + red[3];
  float nrm = sqrtf(tot);
  float rinv = 1.f / fmaxf(nrm, 1e-12f);
  if (tid == 0) normv[row] = nrm;
  bf16* a = Ab + (size_t)row * KB;
  bf16* b = Bb + (size_t)row * KB;
  for (int k = tid; k < JJ; k += 256) {
    bf16 v = (bf16)(g[k] * rinv);
    a[XOFF + k] = v;
    b[XOFF + k] = v;
  }
  if (tid < 28) { a[HH + tid] = (bf16)0.f; b[HH + tid] = (bf16)0.f; }
  if (tid < 48) { a[XOFF + JJ + tid] = (bf16)0.f; b[XOFF + JJ + tid] = (bf16)0.f; }
}

// Per-row: sq = |p|^2 and f = (relu(tanh(sp@W1+b1)@W2+b2)@Wf + bf). Block=128.
__global__ void prep_sf(const float* __restrict__ spos,
                        const float* __restrict__ Ws, const float* __restrict__ bs,
                        const float* __restrict__ W1, const float* __restrict__ b1,
                        const float* __restrict__ W2, const float* __restrict__ b2,
                        const float* __restrict__ Wf, const float* __restrict__ bfp,
                        float* __restrict__ sqv, float* __restrict__ fv)
{
  int row = blockIdx.x, tid = threadIdx.x;
  float px = spos[2 * row], py = spos[2 * row + 1];
  if (tid == 0) sqv[row] = px * px + py * py;
  __shared__ float sp[HH], t1[HH], e2[HH];
  if (tid < HH) sp[tid] = px * Ws[tid] + py * Ws[HH + tid] + bs[tid];
  __syncthreads();
  if (tid < HH) {
    float s = b1[tid];
    for (int gi = 0; gi < HH; ++gi) s += sp[gi] * W1[gi * HH + tid];
    t1[tid] = tanhf(s);
  }
  __syncthreads();
  if (tid < HH) {
    float s = b2[tid];
    for (int gi = 0; gi < HH; ++gi) s += t1[gi] * W2[gi * HH + tid];
    e2[tid] = fmaxf(s, 0.f) * Wf[tid];
  }
  __syncthreads();
  if (tid < 64) {
    float s = e2[tid] + ((tid < 36) ? e2[tid + 64] : 0.f);
#pragma unroll
    for (int m = 32; m >= 1; m >>= 1) s += __shfl_xor(s, m);
    if (tid == 0) fv[row] = s + bfp[0];
  }
}

// WqkT[h,k] = Wq[k,h] (h<100) / Wk[k,h-100] (100<=h<200), zero elsewhere. [256,2048] bf16.
__global__ void pack_wqk(const float* __restrict__ Wq, const float* __restrict__ Wk,
                         bf16* __restrict__ Wt)
{
  int idx = blockIdx.x * 256 + threadIdx.x;
  int h = idx >> 11;
  int k = idx & 2047;
  float v = 0.f;
  if (k < JJ) {
    if (h < HH) v = Wq[(size_t)k * HH + h];
    else if (h < 2 * HH) v = Wk[(size_t)k * HH + (h - HH)];
  }
  Wt[idx] = (bf16)v;
}

// WvT[o, XOFF+j] = Wv[j, o] (bf16), zero-padded j>=JJ. Tiled 32x32 transpose.
__global__ void pack_wvt(const float* __restrict__ Wv, bf16* __restrict__ Wt)
{
  __shared__ float tile[32][33];
  int tx = threadIdx.x & 31, ty = threadIdx.x >> 5;   // 32x8
  int o0 = blockIdx.x * 32, j0 = blockIdx.y * 32;
#pragma unroll
  for (int rr = 0; rr < 32; rr += 8) {
    int j = j0 + ty + rr;
    tile[ty + rr][tx] = (j < JJ) ? Wv[(size_t)j * NN + o0 + tx] : 0.f;
  }
  __syncthreads();
#pragma unroll
  for (int rr = 0; rr < 32; rr += 8) {
    int o = o0 + ty + rr;
    Wt[(size_t)o * KB + XOFF + j0 + tx] = (bf16)tile[tx][ty + rr];
  }
}

__global__ void zero_wvt_head(bf16* __restrict__ Wt)
{
  int idx = blockIdx.x * 256 + threadIdx.x;   // NN*XOFF elements
  int o = idx >> 7, c = idx & 127;
  Wt[(size_t)o * KB + c] = (bf16)0.f;
}

// attn[row, :] = P[row, :] / rowsum[row]
__global__ void norm_attn(const bf16* __restrict__ P, const float* __restrict__ rowsum,
                          float* __restrict__ attn)
{
  int row = blockIdx.x;
  float rinv = 1.f / rowsum[row];
  const bf16x8* p = (const bf16x8*)(P + (size_t)row * NN);
  float* dst = attn + (size_t)row * NN;
  for (int c = threadIdx.x; c < NN / 8; c += 256) {
    bf16x8 v = p[c];
#pragma unroll
    for (int e = 0; e < 8; ++e) dst[c * 8 + e] = (float)v[e] * rinv;
  }
}

extern "C" void kernel_launch(void* const* d_in, const int* in_sizes, int n_in,
                              void* d_out, int out_size, void* d_ws, size_t ws_size,
                              hipStream_t stream)
{
  const float* gene = (const float*)d_in[0];
  const float* spos = (const float*)d_in[1];
  const float* Wq = (const float*)d_in[2];
  const float* bq = (const float*)d_in[3];
  const float* Wk = (const float*)d_in[4];
  const float* bk = (const float*)d_in[5];
  const float* Wv = (const float*)d_in[6];
  const float* bv = (const float*)d_in[7];
  const float* Ws = (const float*)d_in[8];
  const float* bs = (const float*)d_in[9];
  const float* W1 = (const float*)d_in[10];
  const float* b1 = (const float*)d_in[11];
  const float* W2 = (const float*)d_in[12];
  const float* b2 = (const float*)d_in[13];
  const float* Wf = (const float*)d_in[14];
  const float* bfp = (const float*)d_in[15];

  char* ws = (char*)d_ws;
  bf16* Abig = (bf16*)ws;            ws += (size_t)NN * KB * 2;
  bf16* Bbig = (bf16*)ws;            ws += (size_t)NN * KB * 2;
  bf16* WvT  = (bf16*)ws;            ws += (size_t)NN * KB * 2;
  bf16* WqkT = (bf16*)ws;            ws += (size_t)256 * KQK * 2;
  bf16* P    = (bf16*)ws;            ws += (size_t)NN * NN * 2;
  float* rowsum = (float*)ws;        ws += (size_t)NN * 4;
  float* normv  = (float*)ws;        ws += (size_t)NN * 4;
  float* sqv    = (float*)ws;        ws += (size_t)NN * 4;
  float* fv     = (float*)ws;        ws += (size_t)NN * 4;

  float* attn = (float*)d_out;
  float* outp = (float*)d_out + (size_t)NN * NN;
  bf16* Vt = (bf16*)d_out;   // Vt (bf16, 75.5MB) lives in attn region until norm_attn

  hipMemsetAsync(rowsum, 0, NN * sizeof(float), stream);
  prep_xn<<<NN, 256, 0, stream>>>(gene, Abig, Bbig, normv);
  prep_sf<<<NN, 128, 0, stream>>>(spos, Ws, bs, W1, b1, W2, b2, Wf, bfp, sqv, fv);
  pack_wqk<<<(256 * KQK) / 256, 256, 0, stream>>>(Wq, Wk, WqkT);
  pack_wvt<<<dim3(NN / 32, KQK / 32), 256, 0, stream>>>(Wv, WvT);
  zero_wvt_head<<<(NN * XOFF) / 256, 256, 0, stream>>>(WvT);

  // QK projection: reads Abig cols [128,2176) only; writes cols [0,100) of Abig/Bbig
  gemm_bt<3><<<dim3(NN / 128, 2), 256, 0, stream>>>(
      Abig + XOFF, WqkT, KB, KQK, KQK, normv, bq, bk, Abig, Bbig, nullptr, nullptr);
  // merged: z=0 logits->P+rowsum, z=1 Vt; shared B panel, tails pack together
  gemm256_lv<<<dim3(NN / 256, NN / 256, 2), 512, 0, stream>>>(
      Abig, WvT, Bbig, sqv, fv, spos, normv, bv, P, Vt, rowsum);
  // out = (P @ V) / rowsum
  gemm256_pv<<<dim3(NN / 256, NN / 256), 512, 0, stream>>>(P, Vt, rowsum, outp);
  // attn = P / rowsum (overwrites Vt region last)
  norm_attn<<<NN, 256, 0, stream>>>(P, rowsum, attn);
}

// Round 2
// 1223.258 us; speedup vs baseline: 1.0749x; 1.0749x over previous
//
#include <hip/hip_runtime.h>
#include <stdint.h>
#include <math.h>

#define NN 6144
#define JJ 2000
#define HH 100
// Big-K layout: cols [0,100)=Q(or K) block, [100,128)=zero, [128,2128)=xn, [2128,2176)=zero
#define KB 2176
#define XOFF 128
#define KQK 2048   // K for QK-projection GEMM: xn cols (2000) + zero pad, read at A+XOFF

typedef __bf16 bf16;
typedef __bf16 bf16x8 __attribute__((ext_vector_type(8)));
typedef float f32x4 __attribute__((ext_vector_type(4)));

__device__ __forceinline__ void load_lds16(const void* g, void* l) {
  __builtin_amdgcn_global_load_lds(
      (const __attribute__((address_space(1))) void*)(uintptr_t)g,
      (__attribute__((address_space(3))) void*)(uint32_t)(uintptr_t)l,
      16, 0, 0);
}

// ---------------------------------------------------------------------------
// Legacy 128x128 kernel (kept for MODE 3: QK projection, N=256 only).
// ---------------------------------------------------------------------------
template <int MODE>
__global__ __launch_bounds__(256, 2) void gemm_bt(
    const bf16* __restrict__ A, const bf16* __restrict__ B,
    int lda, int ldb, int kdim,
    const float* __restrict__ p0, const float* __restrict__ p1,
    const float* __restrict__ p2,
    bf16* __restrict__ ob0, bf16* __restrict__ ob1,
    float* __restrict__ of0, float* __restrict__ rowsum)
{
  __shared__ alignas(16) bf16 As[128 * 64];
  __shared__ alignas(16) bf16 Bs[128 * 64];

  const int tid = threadIdx.x;
  const int lane = tid & 63;
  const int wv = tid >> 6;
  const int m0 = blockIdx.x * 128;
  const int n0 = blockIdx.y * 128;

  const int srow = lane >> 3;
  const int scol = ((lane & 7) ^ srow) * 8;
  const bf16* gA = A + (size_t)(m0 + wv * 32 + srow) * lda + scol;
  const bf16* gB = B + (size_t)(n0 + wv * 32 + srow) * ldb + scol;
  bf16* lA0 = &As[(wv * 32) * 64];
  bf16* lB0 = &Bs[(wv * 32) * 64];

  const int l15 = lane & 15;
  const int l4 = lane >> 4;
  const int s7 = l15 & 7;
  const int wm = (wv >> 1) * 64;
  const int wn = (wv & 1) * 64;
  const bf16* ra0 = &As[(wm + l15) * 64 + ((l4 ^ s7) * 8)];
  const bf16* ra1 = &As[(wm + l15) * 64 + (((l4 + 4) ^ s7) * 8)];
  const bf16* rb0 = &Bs[(wn + l15) * 64 + ((l4 ^ s7) * 8)];
  const bf16* rb1 = &Bs[(wn + l15) * 64 + (((l4 + 4) ^ s7) * 8)];

  f32x4 acc[4][4];
#pragma unroll
  for (int i = 0; i < 4; ++i)
#pragma unroll
    for (int j = 0; j < 4; ++j) acc[i][j] = {0.f, 0.f, 0.f, 0.f};

  const int kiters = kdim >> 6;
  for (int kt = 0; kt < kiters; ++kt) {
    __syncthreads();
#pragma unroll
    for (int it = 0; it < 4; ++it) {
      load_lds16(gA + (size_t)it * 8 * lda, lA0 + it * 512);
      load_lds16(gB + (size_t)it * 8 * ldb, lB0 + it * 512);
    }
    gA += 64;
    gB += 64;
    __syncthreads();
#pragma unroll
    for (int ks = 0; ks < 2; ++ks) {
      const bf16* ra = ks ? ra1 : ra0;
      const bf16* rb = ks ? rb1 : rb0;
      bf16x8 af[4], bb[4];
#pragma unroll
      for (int i = 0; i < 4; ++i)
        af[i] = *(const bf16x8*)(ra + i * 1024);
#pragma unroll
      for (int j = 0; j < 4; ++j)
        bb[j] = *(const bf16x8*)(rb + j * 1024);
#pragma unroll
      for (int i = 0; i < 4; ++i)
#pragma unroll
        for (int j = 0; j < 4; ++j)
          acc[i][j] = __builtin_amdgcn_mfma_f32_16x16x32_bf16(af[i], bb[j], acc[i][j], 0, 0, 0);
    }
  }

  const int row_base = m0 + wm + l4 * 4;
  const int col_base = n0 + wn + l15;

  if (MODE == 3) {
#pragma unroll
    for (int i = 0; i < 4; ++i) {
#pragma unroll
      for (int r = 0; r < 4; ++r) {
        int row = row_base + i * 16 + r;
        float nm = p0[row];
#pragma unroll
        for (int j = 0; j < 4; ++j) {
          int h = col_base + j * 16;
          float v = acc[i][j][r] * nm;
          if (h < HH) ob0[(size_t)row * KB + h] = (bf16)((v + p1[h]) * 0.1f);
          else if (h < 2 * HH) ob1[(size_t)row * KB + (h - HH)] = (bf16)(v + p2[h - HH]);
        }
      }
    }
  }
}

// ---------------------------------------------------------------------------
// 192x256 8-phase pipelined GEMM core (T2 swizzle + T3/T4 counted-vmcnt + T5).
// C[i,j] = sum_k A[i,k]*B[j,k]; 8 waves (2M x 4N), wave tile 96x64, BK=64.
// Grid: 32x24 = 768 blocks = exactly 3.0 rounds at 1 block/CU (no tail).
// LDS: 2 x (A 192x64 + B 256x64) bf16 = 112 KiB, 16B-chunk XOR swizzle
// (phys_chunk = log_chunk ^ (row&7)); staging pre-swizzles the GLOBAL column.
// Staging = 7 single-call chunks of 64 rows each (A:3, B:4). Per tile T:
//   ph1: (T+1).B2,B3 -> other buf (freed during tile T-1)
//   ph3: (T+2).B0,B1 -> cur buf   (all B reads retired at ph2 lgkm+barrier)
//   ph4: (T+2).A0-A2 -> cur buf   (all A reads retired at ph3 lgkm+barrier)
// Boundary s_waitcnt vmcnt(5): retires all of (T+1), leaves (T+2)'s 5 loads
// in flight across the barrier. Never vmcnt(0) in the main loop.
// NOTE: no sched_barrier(0) -- with compiler-visible ds_reads, hipcc emits
// precise per-MFMA lgkmcnt waits; pinning the order was round-1's serializer.
// ---------------------------------------------------------------------------
__device__ __forceinline__ void gemm192_core(
    const bf16* __restrict__ A, const bf16* __restrict__ B,
    int lda, int ldb, int kdim, int m0, int n0, f32x4 (&acc)[6][4])
{
  __shared__ alignas(16) bf16 As[2][192 * 64];
  __shared__ alignas(16) bf16 Bs[2][256 * 64];

  const int tid = threadIdx.x;
  const int lane = tid & 63;
  const int wv = tid >> 6;        // 0..7
  const int wm = wv >> 2;         // 0..1 (M)
  const int wn = wv & 3;          // 0..3 (N)
  const int l15 = lane & 15;
  const int l4 = lane >> 4;
  const int s7 = lane & 7;
  const int srow = lane >> 3;
  const int scol = ((lane & 7) ^ srow) * 8;

  const bf16* gA = A + (size_t)(m0 + wv * 8 + srow) * lda + scol;
  const bf16* gB = B + (size_t)(n0 + wv * 8 + srow) * ldb + scol;

  const int c0 = (l4 ^ s7) * 8;         // ks=0 swizzled chunk offset (bf16 units)
  const int c1 = ((l4 + 4) ^ s7) * 8;   // ks=1

#pragma unroll
  for (int i = 0; i < 6; ++i)
#pragma unroll
    for (int j = 0; j < 4; ++j) acc[i][j] = {0.f, 0.f, 0.f, 0.f};

  const int kt = kdim >> 6;

  // one call = 512 lanes x 16B = 64 rows x 64 cols
#define STA(bufi, h, T)                                                        \
  load_lds16(gA + (size_t)((h) * 64) * lda + (size_t)(T) * 64,                 \
             &As[(bufi)][((h) * 64 + wv * 8) * 64])
#define STB(bufi, h, T)                                                        \
  load_lds16(gB + (size_t)((h) * 64) * ldb + (size_t)(T) * 64,                 \
             &Bs[(bufi)][((h) * 64 + wv * 8) * 64])

  // prologue: tile0 full (7 calls) + tile1 {B0,B1,A0,A1,A2} (5 calls)
  STB(0, 0, 0); STB(0, 1, 0); STB(0, 2, 0); STB(0, 3, 0);
  STA(0, 0, 0); STA(0, 1, 0); STA(0, 2, 0);
  STB(1, 0, 1); STB(1, 1, 1);
  STA(1, 0, 1); STA(1, 1, 1); STA(1, 2, 1);
  asm volatile("s_waitcnt vmcnt(5)" ::: "memory");   // tile0 resident
  __builtin_amdgcn_s_barrier();

  bf16x8 af[3][2], b0[2][2], b1[2][2];

  for (int t2 = 0; t2 < kt; t2 += 2) {
#pragma unroll
    for (int u = 0; u < 2; ++u) {
      const int T = t2 + u;
      const int buf = u, bufn = u ^ 1;
      const bf16* pA = &As[buf][(wm * 96 + l15) * 64];
      const bf16* pB = &Bs[buf][(wn * 64 + l15) * 64];

      // -------- phase 1: (fm 0-2) x b0; stage (T+1).B2,B3 --------
#pragma unroll
      for (int fm = 0; fm < 3; ++fm) {
        af[fm][0] = *(const bf16x8*)(pA + (fm * 16) * 64 + c0);
        af[fm][1] = *(const bf16x8*)(pA + (fm * 16) * 64 + c1);
      }
#pragma unroll
      for (int fn = 0; fn < 2; ++fn) {
        b0[fn][0] = *(const bf16x8*)(pB + (fn * 16) * 64 + c0);
        b0[fn][1] = *(const bf16x8*)(pB + (fn * 16) * 64 + c1);
      }
      if (T + 1 < kt) { STB(bufn, 2, T + 1); STB(bufn, 3, T + 1); }
      __builtin_amdgcn_s_barrier();
      asm volatile("s_waitcnt lgkmcnt(0)" ::: "memory");
      __builtin_amdgcn_s_setprio(1);
#pragma unroll
      for (int ks = 0; ks < 2; ++ks)
#pragma unroll
        for (int fm = 0; fm < 3; ++fm)
#pragma unroll
          for (int fn = 0; fn < 2; ++fn)
            acc[fm][fn] = __builtin_amdgcn_mfma_f32_16x16x32_bf16(
                af[fm][ks], b0[fn][ks], acc[fm][fn], 0, 0, 0);
      __builtin_amdgcn_s_setprio(0);
      __builtin_amdgcn_s_barrier();

      // -------- phase 2: (fm 0-2) x b1; no stage --------
#pragma unroll
      for (int fn = 0; fn < 2; ++fn) {
        b1[fn][0] = *(const bf16x8*)(pB + ((32 + fn * 16) * 64) + c0);
        b1[fn][1] = *(const bf16x8*)(pB + ((32 + fn * 16) * 64) + c1);
      }
      __builtin_amdgcn_s_barrier();
      asm volatile("s_waitcnt lgkmcnt(0)" ::: "memory");
      __builtin_amdgcn_s_setprio(1);
#pragma unroll
      for (int ks = 0; ks < 2; ++ks)
#pragma unroll
        for (int fm = 0; fm < 3; ++fm)
#pragma unroll
          for (int fn = 0; fn < 2; ++fn)
            acc[fm][2 + fn] = __builtin_amdgcn_mfma_f32_16x16x32_bf16(
                af[fm][ks], b1[fn][ks], acc[fm][2 + fn], 0, 0, 0);
      __builtin_amdgcn_s_setprio(0);
      __builtin_amdgcn_s_barrier();

      // -------- phase 3: (fm 3-5) x b1; stage (T+2).B0,B1 --------
#pragma unroll
      for (int fm = 0; fm < 3; ++fm) {
        af[fm][0] = *(const bf16x8*)(pA + ((48 + fm * 16) * 64) + c0);
        af[fm][1] = *(const bf16x8*)(pA + ((48 + fm * 16) * 64) + c1);
      }
      if (T + 2 < kt) { STB(buf, 0, T + 2); STB(buf, 1, T + 2); }
      __builtin_amdgcn_s_barrier();
      asm volatile("s_waitcnt lgkmcnt(0)" ::: "memory");
      __builtin_amdgcn_s_setprio(1);
#pragma unroll
      for (int ks = 0; ks < 2; ++ks)
#pragma unroll
        for (int fm = 0; fm < 3; ++fm)
#pragma unroll
          for (int fn = 0; fn < 2; ++fn)
            acc[3 + fm][2 + fn] = __builtin_amdgcn_mfma_f32_16x16x32_bf16(
                af[fm][ks], b1[fn][ks], acc[3 + fm][2 + fn], 0, 0, 0);
      __builtin_amdgcn_s_setprio(0);
      __builtin_amdgcn_s_barrier();

      // -------- phase 4: (fm 3-5) x b0; stage (T+2).A0-A2; boundary wait ----
      if (T + 2 < kt) { STA(buf, 0, T + 2); STA(buf, 1, T + 2); STA(buf, 2, T + 2); }
      __builtin_amdgcn_s_barrier();
      __builtin_amdgcn_s_setprio(1);
#pragma unroll
      for (int ks = 0; ks < 2; ++ks)
#pragma unroll
        for (int fm = 0; fm < 3; ++fm)
#pragma unroll
          for (int fn = 0; fn < 2; ++fn)
            acc[3 + fm][fn] = __builtin_amdgcn_mfma_f32_16x16x32_bf16(
                af[fm][ks], b0[fn][ks], acc[3 + fm][fn], 0, 0, 0);
      __builtin_amdgcn_s_setprio(0);
      if (T + 1 < kt) {
        if (T + 2 < kt) asm volatile("s_waitcnt vmcnt(5)" ::: "memory");
        else            asm volatile("s_waitcnt vmcnt(0)" ::: "memory");
      }
      __builtin_amdgcn_s_barrier();
    }
  }
#undef STA
#undef STB
}

// Merged logits (z=0) + V-transpose (z=1) launch: independent GEMMs sharing
// B=Bbig; grid 32x24x2 = 1536 blocks = exactly 6.0 rounds at 1 block/CU.
__global__ __launch_bounds__(512, 2) void gemm256_lv(
    const bf16* __restrict__ Abig, const bf16* __restrict__ WvT,
    const bf16* __restrict__ Bbig,
    const float* __restrict__ sqv, const float* __restrict__ fv,
    const float* __restrict__ spos, const float* __restrict__ normv,
    const float* __restrict__ bv,
    bf16* __restrict__ P, bf16* __restrict__ Vt, float* __restrict__ rowsum)
{
  int lin = blockIdx.y * 32 + blockIdx.x;               // [0,768)
  int swz = (lin & 7) * 96 + (lin >> 3);                // XCD swizzle, 768%8==0
  const int m0 = (swz & 31) * 192;
  const int n0 = (swz >> 5) * 256;
  const bool isl = (blockIdx.z == 0);

  f32x4 acc[6][4];
  gemm192_core(isl ? Abig : WvT, Bbig, KB, KB, KB, m0, n0, acc);

  const int tid = threadIdx.x;
  const int lane = tid & 63;
  const int wv = tid >> 6;
  const int wm = wv >> 2, wn = wv & 3;
  const int l15 = lane & 15, l4 = lane >> 4;
  const int row_base = m0 + wm * 96 + l4 * 4;
  const int col_base = n0 + wn * 64 + l15;

  if (isl) {
    // logits -> P = exp(QK/dk + cos + spatial + fdiff), rowsum atomics
    float sqc[4], fc[4], pxc[4], pyc[4];
#pragma unroll
    for (int j = 0; j < 4; ++j) {
      int c = col_base + j * 16;
      sqc[j] = sqv[c];
      fc[j] = fv[c];
      pxc[j] = spos[2 * c];
      pyc[j] = spos[2 * c + 1];
    }
#pragma unroll
    for (int i = 0; i < 6; ++i) {
#pragma unroll
      for (int r = 0; r < 4; ++r) {
        int row = row_base + i * 16 + r;
        float sqr = sqv[row], fr = fv[row];
        float pxr = spos[2 * row], pyr = spos[2 * row + 1];
        float rs = 0.f;
#pragma unroll
        for (int j = 0; j < 4; ++j) {
          int c = col_base + j * 16;
          float d2 = fmaxf(sqr + sqc[j] - 2.f * (pxr * pxc[j] + pyr * pyc[j]), 0.f);
          float lg = acc[i][j][r] + __expf(-0.5f * d2) + tanhf(fr - fc[j]);
          float e = __expf(lg);
          P[(size_t)row * NN + c] = (bf16)e;
          rs += e;
        }
        rs += __shfl_xor(rs, 1);
        rs += __shfl_xor(rs, 2);
        rs += __shfl_xor(rs, 4);
        rs += __shfl_xor(rs, 8);
        if (l15 == 0) atomicAdd(&rowsum[row], rs);
      }
    }
  } else {
    // Vt = acc*norm[col] + bv[row]
    float nc[4];
#pragma unroll
    for (int j = 0; j < 4; ++j) nc[j] = normv[col_base + j * 16];
#pragma unroll
    for (int i = 0; i < 6; ++i) {
#pragma unroll
      for (int r = 0; r < 4; ++r) {
        int row = row_base + i * 16 + r;
        float bvr = bv[row];
#pragma unroll
        for (int j = 0; j < 4; ++j)
          Vt[(size_t)row * NN + col_base + j * 16] = (bf16)(acc[i][j][r] * nc[j] + bvr);
      }
    }
  }
}

// out = (P @ V) / rowsum; grid 32x24 = 768 blocks = exactly 3.0 rounds.
__global__ __launch_bounds__(512, 2) void gemm256_pv(
    const bf16* __restrict__ Pm, const bf16* __restrict__ Vt,
    const float* __restrict__ rowsum, float* __restrict__ outp)
{
  int lin = blockIdx.y * 32 + blockIdx.x;
  int swz = (lin & 7) * 96 + (lin >> 3);
  const int m0 = (swz & 31) * 192;
  const int n0 = (swz >> 5) * 256;

  f32x4 acc[6][4];
  gemm192_core(Pm, Vt, NN, NN, NN, m0, n0, acc);

  const int tid = threadIdx.x;
  const int lane = tid & 63;
  const int wv = tid >> 6;
  const int wm = wv >> 2, wn = wv & 3;
  const int l15 = lane & 15, l4 = lane >> 4;
  const int row_base = m0 + wm * 96 + l4 * 4;
  const int col_base = n0 + wn * 64 + l15;
#pragma unroll
  for (int i = 0; i < 6; ++i) {
#pragma unroll
    for (int r = 0; r < 4; ++r) {
      int row = row_base + i * 16 + r;
      float rinv = 1.f / rowsum[row];
#pragma unroll
      for (int j = 0; j < 4; ++j)
        outp[(size_t)row * NN + col_base + j * 16] = acc[i][j][r] * rinv;
    }
  }
}

// Per-row gene norm + write xn (bf16) into Abig & Bbig at XOFF, zero pads.
__global__ void prep_xn(const float* __restrict__ gene, bf16* __restrict__ Ab,
                        bf16* __restrict__ Bb, float* __restrict__ normv)
{
  int row = blockIdx.x, tid = threadIdx.x;
  const float* g = gene + (size_t)row * JJ;
  float s = 0.f;
  for (int k = tid; k < JJ; k += 256) { float v = g[k]; s += v * v; }
#pragma unroll
  for (int m = 32; m >= 1; m >>= 1) s += __shfl_xor(s, m);
  __shared__ float red[4];
  if ((tid & 63) == 0) red[tid >> 6] = s;
  __syncthreads();
  float tot = red[0] + red[1] + red[2] + red[3];
  float nrm = sqrtf(tot);
  float rinv = 1.f / fmaxf(nrm, 1e-12f);
  if (tid == 0) normv[row] = nrm;
  bf16* a = Ab + (size_t)row * KB;
  bf16* b = Bb + (size_t)row * KB;
  for (int k = tid; k < JJ; k += 256) {
    bf16 v = (bf16)(g[k] * rinv);
    a[XOFF + k] = v;
    b[XOFF + k] = v;
  }
  if (tid < 28) { a[HH + tid] = (bf16)0.f; b[HH + tid] = (bf16)0.f; }
  if (tid < 48) { a[XOFF + JJ + tid] = (bf16)0.f; b[XOFF + JJ + tid] = (bf16)0.f; }
}

// Per-row: sq = |p|^2 and f = (relu(tanh(sp@W1+b1)@W2+b2)@Wf + bf). Block=128.
__global__ void prep_sf(const float* __restrict__ spos,
                        const float* __restrict__ Ws, const float* __restrict__ bs,
                        const float* __restrict__ W1, const float* __restrict__ b1,
                        const float* __restrict__ W2, const float* __restrict__ b2,
                        const float* __restrict__ Wf, const float* __restrict__ bfp,
                        float* __restrict__ sqv, float* __restrict__ fv)
{
  int row = blockIdx.x, tid = threadIdx.x;
  float px = spos[2 * row], py = spos[2 * row + 1];
  if (tid == 0) sqv[row] = px * px + py * py;
  __shared__ float sp[HH], t1[HH], e2[HH];
  if (tid < HH) sp[tid] = px * Ws[tid] + py * Ws[HH + tid] + bs[tid];
  __syncthreads();
  if (tid < HH) {
    float s = b1[tid];
    for (int gi = 0; gi < HH; ++gi) s += sp[gi] * W1[gi * HH + tid];
    t1[tid] = tanhf(s);
  }
  __syncthreads();
  if (tid < HH) {
    float s = b2[tid];
    for (int gi = 0; gi < HH; ++gi) s += t1[gi] * W2[gi * HH + tid];
    e2[tid] = fmaxf(s, 0.f) * Wf[tid];
  }
  __syncthreads();
  if (tid < 64) {
    float s = e2[tid] + ((tid < 36) ? e2[tid + 64] : 0.f);
#pragma unroll
    for (int m = 32; m >= 1; m >>= 1) s += __shfl_xor(s, m);
    if (tid == 0) fv[row] = s + bfp[0];
  }
}

// WqkT[h,k] = Wq[k,h] (h<100) / Wk[k,h-100] (100<=h<200), zero elsewhere. [256,2048] bf16.
__global__ void pack_wqk(const float* __restrict__ Wq, const float* __restrict__ Wk,
                         bf16* __restrict__ Wt)
{
  int idx = blockIdx.x * 256 + threadIdx.x;
  int h = idx >> 11;
  int k = idx & 2047;
  float v = 0.f;
  if (k < JJ) {
    if (h < HH) v = Wq[(size_t)k * HH + h];
    else if (h < 2 * HH) v = Wk[(size_t)k * HH + (h - HH)];
  }
  Wt[idx] = (bf16)v;
}

// WvT[o, XOFF+j] = Wv[j, o] (bf16), zero-padded j>=JJ. Tiled 32x32 transpose.
__global__ void pack_wvt(const float* __restrict__ Wv, bf16* __restrict__ Wt)
{
  __shared__ float tile[32][33];
  int tx = threadIdx.x & 31, ty = threadIdx.x >> 5;   // 32x8
  int o0 = blockIdx.x * 32, j0 = blockIdx.y * 32;
#pragma unroll
  for (int rr = 0; rr < 32; rr += 8) {
    int j = j0 + ty + rr;
    tile[ty + rr][tx] = (j < JJ) ? Wv[(size_t)j * NN + o0 + tx] : 0.f;
  }
  __syncthreads();
#pragma unroll
  for (int rr = 0; rr < 32; rr += 8) {
    int o = o0 + ty + rr;
    Wt[(size_t)o * KB + XOFF + j0 + tx] = (bf16)tile[tx][ty + rr];
  }
}

__global__ void zero_wvt_head(bf16* __restrict__ Wt)
{
  int idx = blockIdx.x * 256 + threadIdx.x;   // NN*XOFF elements
  int o = idx >> 7, c = idx & 127;
  Wt[(size_t)o * KB + c] = (bf16)0.f;
}

// attn[row, :] = P[row, :] / rowsum[row]
__global__ void norm_attn(const bf16* __restrict__ P, const float* __restrict__ rowsum,
                          float* __restrict__ attn)
{
  int row = blockIdx.x;
  float rinv = 1.f / rowsum[row];
  const bf16x8* p = (const bf16x8*)(P + (size_t)row * NN);
  float* dst = attn + (size_t)row * NN;
  for (int c = threadIdx.x; c < NN / 8; c += 256) {
    bf16x8 v = p[c];
#pragma unroll
    for (int e = 0; e < 8; ++e) dst[c * 8 + e] = (float)v[e] * rinv;
  }
}

extern "C" void kernel_launch(void* const* d_in, const int* in_sizes, int n_in,
                              void* d_out, int out_size, void* d_ws, size_t ws_size,
                              hipStream_t stream)
{
  const float* gene = (const float*)d_in[0];
  const float* spos = (const float*)d_in[1];
  const float* Wq = (const float*)d_in[2];
  const float* bq = (const float*)d_in[3];
  const float* Wk = (const float*)d_in[4];
  const float* bk = (const float*)d_in[5];
  const float* Wv = (const float*)d_in[6];
  const float* bv = (const float*)d_in[7];
  const float* Ws = (const float*)d_in[8];
  const float* bs = (const float*)d_in[9];
  const float* W1 = (const float*)d_in[10];
  const float* b1 = (const float*)d_in[11];
  const float* W2 = (const float*)d_in[12];
  const float* b2 = (const float*)d_in[13];
  const float* Wf = (const float*)d_in[14];
  const float* bfp = (const float*)d_in[15];

  char* ws = (char*)d_ws;
  bf16* Abig = (bf16*)ws;            ws += (size_t)NN * KB * 2;
  bf16* Bbig = (bf16*)ws;            ws += (size_t)NN * KB * 2;
  bf16* WvT  = (bf16*)ws;            ws += (size_t)NN * KB * 2;
  bf16* WqkT = (bf16*)ws;            ws += (size_t)256 * KQK * 2;
  bf16* P    = (bf16*)ws;            ws += (size_t)NN * NN * 2;
  float* rowsum = (float*)ws;        ws += (size_t)NN * 4;
  float* normv  = (float*)ws;        ws += (size_t)NN * 4;
  float* sqv    = (float*)ws;        ws += (size_t)NN * 4;
  float* fv     = (float*)ws;        ws += (size_t)NN * 4;

  float* attn = (float*)d_out;
  float* outp = (float*)d_out + (size_t)NN * NN;
  bf16* Vt = (bf16*)d_out;   // Vt (bf16, 75.5MB) lives in attn region until norm_attn

  hipMemsetAsync(rowsum, 0, NN * sizeof(float), stream);
  prep_xn<<<NN, 256, 0, stream>>>(gene, Abig, Bbig, normv);
  prep_sf<<<NN, 128, 0, stream>>>(spos, Ws, bs, W1, b1, W2, b2, Wf, bfp, sqv, fv);
  pack_wqk<<<(256 * KQK) / 256, 256, 0, stream>>>(Wq, Wk, WqkT);
  pack_wvt<<<dim3(NN / 32, KQK / 32), 256, 0, stream>>>(Wv, WvT);
  zero_wvt_head<<<(NN * XOFF) / 256, 256, 0, stream>>>(WvT);

  // QK projection: reads Abig cols [128,2176) only; writes cols [0,100) of Abig/Bbig
  gemm_bt<3><<<dim3(NN / 128, 2), 256, 0, stream>>>(
      Abig + XOFF, WqkT, KB, KQK, KQK, normv, bq, bk, Abig, Bbig, nullptr, nullptr);
  // merged: z=0 logits->P+rowsum, z=1 Vt; shared B panel, exact 6.0 rounds
  gemm256_lv<<<dim3(32, 24, 2), 512, 0, stream>>>(
      Abig, WvT, Bbig, sqv, fv, spos, normv, bv, P, Vt, rowsum);
  // out = (P @ V) / rowsum; exact 3.0 rounds
  gemm256_pv<<<dim3(32, 24), 512, 0, stream>>>(P, Vt, rowsum, outp);
  // attn = P / rowsum (overwrites Vt region last)
  norm_attn<<<NN, 256, 0, stream>>>(P, rowsum, attn);
}

// Round 3
// 1187.858 us; speedup vs baseline: 1.1070x; 1.0298x over previous
//
#include <hip/hip_runtime.h>
#include <stdint.h>
#include <math.h>

#define NN 6144
#define JJ 2000
#define HH 100
// Big-K layout: cols [0,100)=Q(or K) block, [100,128)=zero, [128,2128)=xn, [2128,2176)=zero
#define KB 2176
#define XOFF 128
#define KQK 2048   // K for QK-projection GEMM: xn cols (2000) + zero pad, read at A+XOFF

typedef __bf16 bf16;
typedef __bf16 bf16x8 __attribute__((ext_vector_type(8)));
typedef float f32x4 __attribute__((ext_vector_type(4)));

__device__ __forceinline__ void load_lds16(const void* g, void* l) {
  __builtin_amdgcn_global_load_lds(
      (const __attribute__((address_space(1))) void*)(uintptr_t)g,
      (__attribute__((address_space(3))) void*)(uint32_t)(uintptr_t)l,
      16, 0, 0);
}

// ---------------------------------------------------------------------------
// Legacy 128x128 kernel (kept for MODE 3: QK projection, N=256 only).
// ---------------------------------------------------------------------------
template <int MODE>
__global__ __launch_bounds__(256, 2) void gemm_bt(
    const bf16* __restrict__ A, const bf16* __restrict__ B,
    int lda, int ldb, int kdim,
    const float* __restrict__ p0, const float* __restrict__ p1,
    const float* __restrict__ p2,
    bf16* __restrict__ ob0, bf16* __restrict__ ob1,
    float* __restrict__ of0, float* __restrict__ rowsum)
{
  __shared__ alignas(16) bf16 As[128 * 64];
  __shared__ alignas(16) bf16 Bs[128 * 64];

  const int tid = threadIdx.x;
  const int lane = tid & 63;
  const int wv = tid >> 6;
  const int m0 = blockIdx.x * 128;
  const int n0 = blockIdx.y * 128;

  const int srow = lane >> 3;
  const int scol = ((lane & 7) ^ srow) * 8;
  const bf16* gA = A + (size_t)(m0 + wv * 32 + srow) * lda + scol;
  const bf16* gB = B + (size_t)(n0 + wv * 32 + srow) * ldb + scol;
  bf16* lA0 = &As[(wv * 32) * 64];
  bf16* lB0 = &Bs[(wv * 32) * 64];

  const int l15 = lane & 15;
  const int l4 = lane >> 4;
  const int s7 = l15 & 7;
  const int wm = (wv >> 1) * 64;
  const int wn = (wv & 1) * 64;
  const bf16* ra0 = &As[(wm + l15) * 64 + ((l4 ^ s7) * 8)];
  const bf16* ra1 = &As[(wm + l15) * 64 + (((l4 + 4) ^ s7) * 8)];
  const bf16* rb0 = &Bs[(wn + l15) * 64 + ((l4 ^ s7) * 8)];
  const bf16* rb1 = &Bs[(wn + l15) * 64 + (((l4 + 4) ^ s7) * 8)];

  f32x4 acc[4][4];
#pragma unroll
  for (int i = 0; i < 4; ++i)
#pragma unroll
    for (int j = 0; j < 4; ++j) acc[i][j] = {0.f, 0.f, 0.f, 0.f};

  const int kiters = kdim >> 6;
  for (int kt = 0; kt < kiters; ++kt) {
    __syncthreads();
#pragma unroll
    for (int it = 0; it < 4; ++it) {
      load_lds16(gA + (size_t)it * 8 * lda, lA0 + it * 512);
      load_lds16(gB + (size_t)it * 8 * ldb, lB0 + it * 512);
    }
    gA += 64;
    gB += 64;
    __syncthreads();
#pragma unroll
    for (int ks = 0; ks < 2; ++ks) {
      const bf16* ra = ks ? ra1 : ra0;
      const bf16* rb = ks ? rb1 : rb0;
      bf16x8 af[4], bb[4];
#pragma unroll
      for (int i = 0; i < 4; ++i)
        af[i] = *(const bf16x8*)(ra + i * 1024);
#pragma unroll
      for (int j = 0; j < 4; ++j)
        bb[j] = *(const bf16x8*)(rb + j * 1024);
#pragma unroll
      for (int i = 0; i < 4; ++i)
#pragma unroll
        for (int j = 0; j < 4; ++j)
          acc[i][j] = __builtin_amdgcn_mfma_f32_16x16x32_bf16(af[i], bb[j], acc[i][j], 0, 0, 0);
    }
  }

  const int row_base = m0 + wm + l4 * 4;
  const int col_base = n0 + wn + l15;

  if (MODE == 3) {
#pragma unroll
    for (int i = 0; i < 4; ++i) {
#pragma unroll
      for (int r = 0; r < 4; ++r) {
        int row = row_base + i * 16 + r;
        float nm = p0[row];
#pragma unroll
        for (int j = 0; j < 4; ++j) {
          int h = col_base + j * 16;
          float v = acc[i][j][r] * nm;
          if (h < HH) ob0[(size_t)row * KB + h] = (bf16)((v + p1[h]) * 0.1f);
          else if (h < 2 * HH) ob1[(size_t)row * KB + (h - HH)] = (bf16)(v + p2[h - HH]);
        }
      }
    }
  }
}

// ---------------------------------------------------------------------------
// 192x256 2-phase-per-K-tile pipelined GEMM core.
// C[i,j] = sum_k A[i,k]*B[j,k]; 8 waves (2M x 4N), wave tile 96x64, BK=64.
// Grid: 32x24 = 768 blocks = exactly 3.0 rounds at 1 block/CU (no tail).
// LDS: 2 x (A 192x64 + B 256x64) bf16 = 112 KiB, 16B-chunk XOR swizzle
// (phys_chunk = log_chunk ^ (row&7)); staging pre-swizzles the GLOBAL column.
//
// Phase-count rationale: rounds 1-2 measured a FIXED ~70cy overhead per phase
// independent of phase MFMA count (16-MFMA phases: 154cy; 12-MFMA: 126cy).
// 2 phases/K-tile (24 MFMA each) amortizes it 2x better than 4 phases.
//
// Per tile T (buf c=T&1):
//  ph1: ALL 20 ds_reads (af 12, b0 4, b1 4); stage A(T+1)->As[c^1] (3 calls);
//       24 MFMA (fm0-5 x b0); lgkmcnt(0); barrier.
//       [As[c^1] reads drained at T-1.ph1 barrier; b1 lands in regs so Bs[c]
//        is fully sampled at THIS phase's lgkm(0)+barrier]
//  ph2: stage B(T+2)->Bs[c] (4 calls; legal: Bs[c] drained at ph1 barrier);
//       24 MFMA (fm0-5 x b1); boundary s_waitcnt vmcnt(4); barrier.
//       [vmcnt(4): retires A(T+1),B(T+1); leaves B(T+2)'s 4 calls in flight]
// Stage leads = 2 full phases (~600cy) -> covers L3 latency. Never vmcnt(0)
// in the main loop. No sched_barrier / pre-MFMA drain: compiler-visible
// ds_reads get precise per-MFMA lgkmcnt waits and free interleaving.
// ---------------------------------------------------------------------------
__device__ __forceinline__ void gemm192_core(
    const bf16* __restrict__ A, const bf16* __restrict__ B,
    int lda, int ldb, int kdim, int m0, int n0, f32x4 (&acc)[6][4])
{
  __shared__ alignas(16) bf16 As[2][192 * 64];
  __shared__ alignas(16) bf16 Bs[2][256 * 64];

  const int tid = threadIdx.x;
  const int lane = tid & 63;
  const int wv = tid >> 6;        // 0..7
  const int wm = wv >> 2;         // 0..1 (M)
  const int wn = wv & 3;          // 0..3 (N)
  const int l15 = lane & 15;
  const int l4 = lane >> 4;
  const int s7 = lane & 7;
  const int srow = lane >> 3;
  const int scol = ((lane & 7) ^ srow) * 8;

  const bf16* gA = A + (size_t)(m0 + wv * 8 + srow) * lda + scol;
  const bf16* gB = B + (size_t)(n0 + wv * 8 + srow) * ldb + scol;

  const int c0 = (l4 ^ s7) * 8;         // ks=0 swizzled chunk offset (bf16 units)
  const int c1 = ((l4 + 4) ^ s7) * 8;   // ks=1

#pragma unroll
  for (int i = 0; i < 6; ++i)
#pragma unroll
    for (int j = 0; j < 4; ++j) acc[i][j] = {0.f, 0.f, 0.f, 0.f};

  const int kt = kdim >> 6;   // always even here (96 / 34)

  // one call = 512 lanes x 16B = 64 rows x 64 cols
#define STA(bufi, h, T)                                                        \
  load_lds16(gA + (size_t)((h) * 64) * lda + (size_t)(T) * 64,                 \
             &As[(bufi)][((h) * 64 + wv * 8) * 64])
#define STB(bufi, h, T)                                                        \
  load_lds16(gB + (size_t)((h) * 64) * ldb + (size_t)(T) * 64,                 \
             &Bs[(bufi)][((h) * 64 + wv * 8) * 64])

  // prologue: A(0), B(0) (7 calls), then B(1) (4 calls)
  STA(0, 0, 0); STA(0, 1, 0); STA(0, 2, 0);
  STB(0, 0, 0); STB(0, 1, 0); STB(0, 2, 0); STB(0, 3, 0);
  STB(1, 0, 1); STB(1, 1, 1); STB(1, 2, 1); STB(1, 3, 1);
  asm volatile("s_waitcnt vmcnt(4)" ::: "memory");   // tile0 resident
  __builtin_amdgcn_s_barrier();

  bf16x8 af[6][2], b0[2][2], b1[2][2];

  for (int t2 = 0; t2 < kt; t2 += 2) {
#pragma unroll
    for (int u = 0; u < 2; ++u) {
      const int T = t2 + u;
      const int buf = u, bufn = u ^ 1;
      const bf16* pA = &As[buf][(wm * 96 + l15) * 64];
      const bf16* pB = &Bs[buf][(wn * 64 + l15) * 64];

      // -------- phase 1: all reads; stage A(T+1); MFMA fm x b0 --------
#pragma unroll
      for (int fm = 0; fm < 6; ++fm) {
        af[fm][0] = *(const bf16x8*)(pA + (fm * 16) * 64 + c0);
        af[fm][1] = *(const bf16x8*)(pA + (fm * 16) * 64 + c1);
      }
#pragma unroll
      for (int fn = 0; fn < 2; ++fn) {
        b0[fn][0] = *(const bf16x8*)(pB + (fn * 16) * 64 + c0);
        b0[fn][1] = *(const bf16x8*)(pB + (fn * 16) * 64 + c1);
        b1[fn][0] = *(const bf16x8*)(pB + ((32 + fn * 16) * 64) + c0);
        b1[fn][1] = *(const bf16x8*)(pB + ((32 + fn * 16) * 64) + c1);
      }
      if (T + 1 < kt) { STA(bufn, 0, T + 1); STA(bufn, 1, T + 1); STA(bufn, 2, T + 1); }
      __builtin_amdgcn_s_setprio(1);
#pragma unroll
      for (int ks = 0; ks < 2; ++ks)
#pragma unroll
        for (int fm = 0; fm < 6; ++fm)
#pragma unroll
          for (int fn = 0; fn < 2; ++fn)
            acc[fm][fn] = __builtin_amdgcn_mfma_f32_16x16x32_bf16(
                af[fm][ks], b0[fn][ks], acc[fm][fn], 0, 0, 0);
      __builtin_amdgcn_s_setprio(0);
      asm volatile("s_waitcnt lgkmcnt(0)" ::: "memory");  // b1 reads drained too
      __builtin_amdgcn_s_barrier();

      // -------- phase 2: stage B(T+2); MFMA fm x b1; boundary --------
      if (T + 2 < kt) { STB(buf, 0, T + 2); STB(buf, 1, T + 2);
                        STB(buf, 2, T + 2); STB(buf, 3, T + 2); }
      __builtin_amdgcn_s_setprio(1);
#pragma unroll
      for (int ks = 0; ks < 2; ++ks)
#pragma unroll
        for (int fm = 0; fm < 6; ++fm)
#pragma unroll
          for (int fn = 0; fn < 2; ++fn)
            acc[fm][2 + fn] = __builtin_amdgcn_mfma_f32_16x16x32_bf16(
                af[fm][ks], b1[fn][ks], acc[fm][2 + fn], 0, 0, 0);
      __builtin_amdgcn_s_setprio(0);
      if (T + 1 < kt) {
        if (T + 2 < kt) asm volatile("s_waitcnt vmcnt(4)" ::: "memory");
        else            asm volatile("s_waitcnt vmcnt(0)" ::: "memory");
      }
      __builtin_amdgcn_s_barrier();
    }
  }
#undef STA
#undef STB
}

// Merged logits (z=0) + V-transpose (z=1) launch: independent GEMMs sharing
// B=Bbig; grid 32x24x2 = 1536 blocks = exactly 6.0 rounds at 1 block/CU.
__global__ __launch_bounds__(512, 2) void gemm256_lv(
    const bf16* __restrict__ Abig, const bf16* __restrict__ WvT,
    const bf16* __restrict__ Bbig,
    const float* __restrict__ sqv, const float* __restrict__ fv,
    const float* __restrict__ spos, const float* __restrict__ normv,
    const float* __restrict__ bv,
    bf16* __restrict__ P, bf16* __restrict__ Vt, float* __restrict__ rowsum)
{
  int lin = blockIdx.y * 32 + blockIdx.x;               // [0,768)
  int swz = (lin & 7) * 96 + (lin >> 3);                // XCD swizzle, 768%8==0
  const int m0 = (swz & 31) * 192;
  const int n0 = (swz >> 5) * 256;
  const bool isl = (blockIdx.z == 0);

  f32x4 acc[6][4];
  gemm192_core(isl ? Abig : WvT, Bbig, KB, KB, KB, m0, n0, acc);

  const int tid = threadIdx.x;
  const int lane = tid & 63;
  const int wv = tid >> 6;
  const int wm = wv >> 2, wn = wv & 3;
  const int l15 = lane & 15, l4 = lane >> 4;
  const int row_base = m0 + wm * 96 + l4 * 4;
  const int col_base = n0 + wn * 64 + l15;

  if (isl) {
    // logits -> P = exp(QK/dk + cos + spatial + fdiff), rowsum atomics
    float sqc[4], fc[4], pxc[4], pyc[4];
#pragma unroll
    for (int j = 0; j < 4; ++j) {
      int c = col_base + j * 16;
      sqc[j] = sqv[c];
      fc[j] = fv[c];
      pxc[j] = spos[2 * c];
      pyc[j] = spos[2 * c + 1];
    }
#pragma unroll
    for (int i = 0; i < 6; ++i) {
#pragma unroll
      for (int r = 0; r < 4; ++r) {
        int row = row_base + i * 16 + r;
        float sqr = sqv[row], fr = fv[row];
        float pxr = spos[2 * row], pyr = spos[2 * row + 1];
        float rs = 0.f;
#pragma unroll
        for (int j = 0; j < 4; ++j) {
          int c = col_base + j * 16;
          float d2 = fmaxf(sqr + sqc[j] - 2.f * (pxr * pxc[j] + pyr * pyc[j]), 0.f);
          float lg = acc[i][j][r] + __expf(-0.5f * d2) + tanhf(fr - fc[j]);
          float e = __expf(lg);
          P[(size_t)row * NN + c] = (bf16)e;
          rs += e;
        }
        rs += __shfl_xor(rs, 1);
        rs += __shfl_xor(rs, 2);
        rs += __shfl_xor(rs, 4);
        rs += __shfl_xor(rs, 8);
        if (l15 == 0) atomicAdd(&rowsum[row], rs);
      }
    }
  } else {
    // Vt = acc*norm[col] + bv[row]
    float nc[4];
#pragma unroll
    for (int j = 0; j < 4; ++j) nc[j] = normv[col_base + j * 16];
#pragma unroll
    for (int i = 0; i < 6; ++i) {
#pragma unroll
      for (int r = 0; r < 4; ++r) {
        int row = row_base + i * 16 + r;
        float bvr = bv[row];
#pragma unroll
        for (int j = 0; j < 4; ++j)
          Vt[(size_t)row * NN + col_base + j * 16] = (bf16)(acc[i][j][r] * nc[j] + bvr);
      }
    }
  }
}

// out = (P @ V) / rowsum; grid 32x24 = 768 blocks = exactly 3.0 rounds.
// outp stores are NON-TEMPORAL: 151MB of never-re-read output would otherwise
// evict the 151MB P+Vt read set from the 256MB L3 (round-2 FETCH_SIZE showed
// 922MB HBM refetch of a 151MB working set).
__global__ __launch_bounds__(512, 2) void gemm256_pv(
    const bf16* __restrict__ Pm, const bf16* __restrict__ Vt,
    const float* __restrict__ rowsum, float* __restrict__ outp)
{
  int lin = blockIdx.y * 32 + blockIdx.x;
  int swz = (lin & 7) * 96 + (lin >> 3);
  const int m0 = (swz & 31) * 192;
  const int n0 = (swz >> 5) * 256;

  f32x4 acc[6][4];
  gemm192_core(Pm, Vt, NN, NN, NN, m0, n0, acc);

  const int tid = threadIdx.x;
  const int lane = tid & 63;
  const int wv = tid >> 6;
  const int wm = wv >> 2, wn = wv & 3;
  const int l15 = lane & 15, l4 = lane >> 4;
  const int row_base = m0 + wm * 96 + l4 * 4;
  const int col_base = n0 + wn * 64 + l15;
#pragma unroll
  for (int i = 0; i < 6; ++i) {
#pragma unroll
    for (int r = 0; r < 4; ++r) {
      int row = row_base + i * 16 + r;
      float rinv = 1.f / rowsum[row];
#pragma unroll
      for (int j = 0; j < 4; ++j)
        __builtin_nontemporal_store(acc[i][j][r] * rinv,
                                    &outp[(size_t)row * NN + col_base + j * 16]);
    }
  }
}

// Per-row gene norm + write xn (bf16) into Abig & Bbig at XOFF, zero pads.
__global__ void prep_xn(const float* __restrict__ gene, bf16* __restrict__ Ab,
                        bf16* __restrict__ Bb, float* __restrict__ normv)
{
  int row = blockIdx.x, tid = threadIdx.x;
  const float* g = gene + (size_t)row * JJ;
  float s = 0.f;
  for (int k = tid; k < JJ; k += 256) { float v = g[k]; s += v * v; }
#pragma unroll
  for (int m = 32; m >= 1; m >>= 1) s += __shfl_xor(s, m);
  __shared__ float red[4];
  if ((tid & 63) == 0) red[tid >> 6] = s;
  __syncthreads();
  float tot = red[0] + red[1] + red[2] + red[3];
  float nrm = sqrtf(tot);
  float rinv = 1.f / fmaxf(nrm, 1e-12f);
  if (tid == 0) normv[row] = nrm;
  bf16* a = Ab + (size_t)row * KB;
  bf16* b = Bb + (size_t)row * KB;
  for (int k = tid; k < JJ; k += 256) {
    bf16 v = (bf16)(g[k] * rinv);
    a[XOFF + k] = v;
    b[XOFF + k] = v;
  }
  if (tid < 28) { a[HH + tid] = (bf16)0.f; b[HH + tid] = (bf16)0.f; }
  if (tid < 48) { a[XOFF + JJ + tid] = (bf16)0.f; b[XOFF + JJ + tid] = (bf16)0.f; }
}

// Per-row: sq = |p|^2 and f = (relu(tanh(sp@W1+b1)@W2+b2)@Wf + bf). Block=128.
__global__ void prep_sf(const float* __restrict__ spos,
                        const float* __restrict__ Ws, const float* __restrict__ bs,
                        const float* __restrict__ W1, const float* __restrict__ b1,
                        const float* __restrict__ W2, const float* __restrict__ b2,
                        const float* __restrict__ Wf, const float* __restrict__ bfp,
                        float* __restrict__ sqv, float* __restrict__ fv)
{
  int row = blockIdx.x, tid = threadIdx.x;
  float px = spos[2 * row], py = spos[2 * row + 1];
  if (tid == 0) sqv[row] = px * px + py * py;
  __shared__ float sp[HH], t1[HH], e2[HH];
  if (tid < HH) sp[tid] = px * Ws[tid] + py * Ws[HH + tid] + bs[tid];
  __syncthreads();
  if (tid < HH) {
    float s = b1[tid];
    for (int gi = 0; gi < HH; ++gi) s += sp[gi] * W1[gi * HH + tid];
    t1[tid] = tanhf(s);
  }
  __syncthreads();
  if (tid < HH) {
    float s = b2[tid];
    for (int gi = 0; gi < HH; ++gi) s += t1[gi] * W2[gi * HH + tid];
    e2[tid] = fmaxf(s, 0.f) * Wf[tid];
  }
  __syncthreads();
  if (tid < 64) {
    float s = e2[tid] + ((tid < 36) ? e2[tid + 64] : 0.f);
#pragma unroll
    for (int m = 32; m >= 1; m >>= 1) s += __shfl_xor(s, m);
    if (tid == 0) fv[row] = s + bfp[0];
  }
}

// WqkT[h,k] = Wq[k,h] (h<100) / Wk[k,h-100] (100<=h<200), zero elsewhere. [256,2048] bf16.
__global__ void pack_wqk(const float* __restrict__ Wq, const float* __restrict__ Wk,
                         bf16* __restrict__ Wt)
{
  int idx = blockIdx.x * 256 + threadIdx.x;
  int h = idx >> 11;
  int k = idx & 2047;
  float v = 0.f;
  if (k < JJ) {
    if (h < HH) v = Wq[(size_t)k * HH + h];
    else if (h < 2 * HH) v = Wk[(size_t)k * HH + (h - HH)];
  }
  Wt[idx] = (bf16)v;
}

// WvT[o, XOFF+j] = Wv[j, o] (bf16), zero-padded j>=JJ. Tiled 32x32 transpose.
__global__ void pack_wvt(const float* __restrict__ Wv, bf16* __restrict__ Wt)
{
  __shared__ float tile[32][33];
  int tx = threadIdx.x & 31, ty = threadIdx.x >> 5;   // 32x8
  int o0 = blockIdx.x * 32, j0 = blockIdx.y * 32;
#pragma unroll
  for (int rr = 0; rr < 32; rr += 8) {
    int j = j0 + ty + rr;
    tile[ty + rr][tx] = (j < JJ) ? Wv[(size_t)j * NN + o0 + tx] : 0.f;
  }
  __syncthreads();
#pragma unroll
  for (int rr = 0; rr < 32; rr += 8) {
    int o = o0 + ty + rr;
    Wt[(size_t)o * KB + XOFF + j0 + tx] = (bf16)tile[tx][ty + rr];
  }
}

__global__ void zero_wvt_head(bf16* __restrict__ Wt)
{
  int idx = blockIdx.x * 256 + threadIdx.x;   // NN*XOFF elements
  int o = idx >> 7, c = idx & 127;
  Wt[(size_t)o * KB + c] = (bf16)0.f;
}

// attn[row, :] = P[row, :] / rowsum[row]; NT stores (attn never re-read).
__global__ void norm_attn(const bf16* __restrict__ P, const float* __restrict__ rowsum,
                          float* __restrict__ attn)
{
  int row = blockIdx.x;
  float rinv = 1.f / rowsum[row];
  const bf16x8* p = (const bf16x8*)(P + (size_t)row * NN);
  float* dst = attn + (size_t)row * NN;
  for (int c = threadIdx.x; c < NN / 8; c += 256) {
    bf16x8 v = p[c];
#pragma unroll
    for (int e = 0; e < 8; ++e)
      __builtin_nontemporal_store((float)v[e] * rinv, &dst[c * 8 + e]);
  }
}

extern "C" void kernel_launch(void* const* d_in, const int* in_sizes, int n_in,
                              void* d_out, int out_size, void* d_ws, size_t ws_size,
                              hipStream_t stream)
{
  const float* gene = (const float*)d_in[0];
  const float* spos = (const float*)d_in[1];
  const float* Wq = (const float*)d_in[2];
  const float* bq = (const float*)d_in[3];
  const float* Wk = (const float*)d_in[4];
  const float* bk = (const float*)d_in[5];
  const float* Wv = (const float*)d_in[6];
  const float* bv = (const float*)d_in[7];
  const float* Ws = (const float*)d_in[8];
  const float* bs = (const float*)d_in[9];
  const float* W1 = (const float*)d_in[10];
  const float* b1 = (const float*)d_in[11];
  const float* W2 = (const float*)d_in[12];
  const float* b2 = (const float*)d_in[13];
  const float* Wf = (const float*)d_in[14];
  const float* bfp = (const float*)d_in[15];

  char* ws = (char*)d_ws;
  bf16* Abig = (bf16*)ws;            ws += (size_t)NN * KB * 2;
  bf16* Bbig = (bf16*)ws;            ws += (size_t)NN * KB * 2;
  bf16* WvT  = (bf16*)ws;            ws += (size_t)NN * KB * 2;
  bf16* WqkT = (bf16*)ws;            ws += (size_t)256 * KQK * 2;
  bf16* P    = (bf16*)ws;            ws += (size_t)NN * NN * 2;
  float* rowsum = (float*)ws;        ws += (size_t)NN * 4;
  float* normv  = (float*)ws;        ws += (size_t)NN * 4;
  float* sqv    = (float*)ws;        ws += (size_t)NN * 4;
  float* fv     = (float*)ws;        ws += (size_t)NN * 4;

  float* attn = (float*)d_out;
  float* outp = (float*)d_out + (size_t)NN * NN;
  bf16* Vt = (bf16*)d_out;   // Vt (bf16, 75.5MB) lives in attn region until norm_attn

  hipMemsetAsync(rowsum, 0, NN * sizeof(float), stream);
  prep_xn<<<NN, 256, 0, stream>>>(gene, Abig, Bbig, normv);
  prep_sf<<<NN, 128, 0, stream>>>(spos, Ws, bs, W1, b1, W2, b2, Wf, bfp, sqv, fv);
  pack_wqk<<<(256 * KQK) / 256, 256, 0, stream>>>(Wq, Wk, WqkT);
  pack_wvt<<<dim3(NN / 32, KQK / 32), 256, 0, stream>>>(Wv, WvT);
  zero_wvt_head<<<(NN * XOFF) / 256, 256, 0, stream>>>(WvT);

  // QK projection: reads Abig cols [128,2176) only; writes cols [0,100) of Abig/Bbig
  gemm_bt<3><<<dim3(NN / 128, 2), 256, 0, stream>>>(
      Abig + XOFF, WqkT, KB, KQK, KQK, normv, bq, bk, Abig, Bbig, nullptr, nullptr);
  // merged: z=0 logits->P+rowsum, z=1 Vt; shared B panel, exact 6.0 rounds
  gemm256_lv<<<dim3(32, 24, 2), 512, 0, stream>>>(
      Abig, WvT, Bbig, sqv, fv, spos, normv, bv, P, Vt, rowsum);
  // out = (P @ V) / rowsum; exact 3.0 rounds
  gemm256_pv<<<dim3(32, 24), 512, 0, stream>>>(P, Vt, rowsum, outp);
  // attn = P / rowsum (overwrites Vt region last)
  norm_attn<<<NN, 256, 0, stream>>>(P, rowsum, attn);
}